// Round 1
// baseline (418.971 us; speedup 1.0000x reference)
//
#include <hip/hip_runtime.h>

// MS-SSIM loss, 5 levels.
// R11: persistent rolling-window blocks for L0/L1. Theory: L0 was latency-
//   bound (VALUBusy 30%, HBM 10%, occ 21.5%) -- per-block cold start
//   (load ~900cy -> H -> barrier(vmcnt0) -> V) paid 6144x with ~2.5
//   blocks/CU residency. Fix: block owns a 64x(32*NSUB) strip, 42-row
//   rolling LDS window; per subtile H computes only the 32 NEW rows
//   (halo reuse, H work 1.31x -> 1.08x), next subtile's global loads
//   issued a full V-phase ahead of use so the syncthreads vmcnt-drain
//   finds them landed. LDS: (hx,hy,hxx,hyy) packed float4, pitch 64,
//   col ^ (row&31) swizzle (dense full-wave permutation, conflict-free
//   b128, alias-free); hxy pitch 65 (bank step 1). 53928 B -> 3 blocks/CU.
//   launch_bounds(256,3) caps at 168 VGPR for 12 waves/CU.
// Carried (counter-verified): spread atomics 1 line/slot (R7: 1093->298);
// padded pyramid + zpad row-select; fastp block-uniform edge path;
// pool loads issued early / stored late; tiny memset.

#define TW 64
#define NIMG 48
#define WIN 42                 // rolling window rows (32 + 10)
#define PQ  64                 // float4 pitch, packed (hx,hy,hxx,hyy), XOR-swizzled
#define P4  65                 // float pitch, hxy plane (bank step 1)
#define P2 63                  // old kernel: float2 pitch
#define P1 62                  // old kernel: float pitch
#define NSLOT 256
#define SSTRIDE 16             // 64 B between slots -> 1 cache line each

typedef float v2f __attribute__((ext_vector_type(2)));
typedef float v4f __attribute__((ext_vector_type(4)));

__device__ __forceinline__ void h_load(
    const float* __restrict__ xi, const float* __restrict__ yi,
    const float* __restrict__ zpad, int gr, int gc0, int H, int W,
    bool fastp, int rowStride, float* xv, float* yv)
{
    const bool rok = ((unsigned)gr < (unsigned)H);
    if (fastp) {
        const float* px = rok ? (xi + (long)gr * rowStride + gc0) : zpad;
        const float* py = rok ? (yi + (long)gr * rowStride + gc0) : zpad;
#pragma unroll
        for (int v = 0; v < 6; ++v) {
            const float4 a = reinterpret_cast<const float4*>(px)[v];
            const float4 b = reinterpret_cast<const float4*>(py)[v];
            xv[4*v+0]=a.x; xv[4*v+1]=a.y; xv[4*v+2]=a.z; xv[4*v+3]=a.w;
            yv[4*v+0]=b.x; yv[4*v+1]=b.y; yv[4*v+2]=b.z; yv[4*v+3]=b.w;
        }
    } else {
        const float* xrow = xi + (long)gr * rowStride;
        const float* yrow = yi + (long)gr * rowStride;
#pragma unroll
        for (int k = 3; k < 21; ++k) {
            const int gc = gc0 + k;
            const bool ok = rok && ((unsigned)gc < (unsigned)W);
            xv[k] = ok ? xrow[gc] : 0.0f;
            yv[k] = ok ? yrow[gc] : 0.0f;
        }
    }
}

__device__ __forceinline__ void h_conv_write(
    const float* xv, const float* yv, v4f* smA, float* smB,
    int slot, int cb, const float* G)
{
    v2f s01[8], s23[8];
    float s4[8];
#pragma unroll
    for (int j = 0; j < 8; ++j) {
        s01[j] = {0.f, 0.f}; s23[j] = {0.f, 0.f}; s4[j] = 0.f;
    }
    // scatter-accumulate: tap position m feeds outputs j in [m-10, m]
#pragma unroll
    for (int m = 0; m < 18; ++m) {
        const float a = xv[m+3], b = yv[m+3];
        v2f w;  w.x  = a;   w.y  = b;
        v2f w2; w2.x = a*a; w2.y = b*b;
        const float ab = a * b;
#pragma unroll
        for (int j = 0; j < 8; ++j) {
            if (j <= m && m - j <= 10) {
                const float g = G[m - j];
                s01[j] += w * g;                    // v_pk_fma_f32
                s23[j] += w2 * g;                   // v_pk_fma_f32
                s4[j] = fmaf(g, ab, s4[j]);
            }
        }
    }
    const int u = slot & 31;
#pragma unroll
    for (int j = 0; j < 8; ++j) {
        v4f o; o.x = s01[j].x; o.y = s01[j].y; o.z = s23[j].x; o.w = s23[j].y;
        smA[slot * PQ + ((cb + j) ^ u)] = o;        // ds_write_b128
        smB[slot * P4 + cb + j] = s4[j];
    }
}

template <int NSUB>
__global__ __launch_bounds__(256, 3) void ssim_rolling_kernel(
    const float* __restrict__ x, const float* __restrict__ y,
    long imgStride, int rowStride,
    float* __restrict__ dsx, float* __restrict__ dsy,
    long dsImgStride, int dsRowStride,
    const float* __restrict__ zpad,
    float* __restrict__ slots, int H, int W, int pad, int do_ds)
{
    const float G[11] = {
        0.00102839f, 0.00759877f, 0.03600077f, 0.10936069f, 0.21300539f,
        0.26601173f, 0.21300539f, 0.10936069f, 0.03600077f, 0.00759877f,
        0.00102839f};
    const float C1 = 4.0e-4f;
    const float C2 = 3.6e-3f;

    __shared__ __align__(16) v4f smA[WIN * PQ];   // (hx,hy,hxx,hyy) swizzled
    __shared__ float             smB[WIN * P4];   // hxy

    const int t   = threadIdx.x;
    const int img = blockIdx.z;
    const int C0  = blockIdx.x * TW;
    const int S0  = blockIdx.y * (NSUB * 32);     // strip start row
    const float* xi = x + (long)img * imgStride;
    const float* yi = y + (long)img * imgStride;
    const bool fastp = pad || ((C0 >= 8) && (C0 + TW + 8 <= W));

    // ---- prologue: fill window slots 0..41 with h-rows [S0-5, S0+37) ----
    for (int s = t; s < WIN * 8; s += 256) {
        const int r = s % WIN, q = s / WIN;
        float pxv[24], pyv[24];
        h_load(xi, yi, zpad, S0 + r - 5, C0 + (q << 3) - 8, H, W, fastp,
               rowStride, pxv, pyv);
        h_conv_write(pxv, pyv, smA, smB, r, q << 3, G);
    }
    __syncthreads();

    const int c   = t & 63;
    const int rr0 = (t >> 6) * 8;                 // wave-uniform
    const int hr  = t & 31, hq = t >> 5;
    const int hgc0 = C0 + (hq << 3) - 8;
    int wslot = hr;                               // H-write slot, (32*tt+hr) mod 42
    int vb    = rr0;                              // V base slot,  (32*tt+rr0) mod 42
    float local = 0.f;
    const int dsW = W >> 1, dsH = H >> 1;
    const long dbase = (long)img * dsImgStride;

    float xv[24], yv[24];                         // next-subtile H rows (in flight)

    for (int tt = 0; tt < NSUB; ++tt) {
        const int R0 = S0 + 32 * tt;

        // (A) issue next subtile's H loads -- consumed only after barrier C
        if (tt < NSUB - 1)
            h_load(xi, yi, zpad, R0 + 37 + hr, hgc0, H, W, fastp, rowStride,
                   xv, yv);

        // (B) pool loads (compute+store deferred past barrier C)
        float2 pa0[2], pa1[2], pb0[2], pb1[2];
        if (do_ds) {
#pragma unroll
            for (int ii = 0; ii < 2; ++ii) {
                const int i  = t + (ii << 8);
                const int dr = i >> 5, dc = i & 31;
                const int gr2 = (R0 >> 1) + dr, gc2 = (C0 >> 1) + dc;
                if (gr2 < dsH && gc2 < dsW) {
                    const float* sx = xi + (long)(2*gr2) * rowStride + 2*gc2;
                    const float* sy = yi + (long)(2*gr2) * rowStride + 2*gc2;
                    pa0[ii] = *reinterpret_cast<const float2*>(sx);
                    pa1[ii] = *reinterpret_cast<const float2*>(sx + rowStride);
                    pb0[ii] = *reinterpret_cast<const float2*>(sy);
                    pb1[ii] = *reinterpret_cast<const float2*>(sy + rowStride);
                }
            }
        }

        // (C) V phase: 18 b128 + 18 b32 reads, scatter-accumulate conv
        v4f accA[8]; float acc4[8];
#pragma unroll
        for (int i = 0; i < 8; ++i) {
            accA[i] = {0.f, 0.f, 0.f, 0.f}; acc4[i] = 0.f;
        }
        int sl = __builtin_amdgcn_readfirstlane(vb);
#pragma unroll
        for (int k = 0; k < 18; ++k) {
            const v4f  h  = smA[sl * PQ + (c ^ (sl & 31))];
            const float hb = smB[sl * P4 + c];
#pragma unroll
            for (int i = 0; i < 8; ++i) {
                if (i <= k && k - i <= 10) {
                    const float g = G[k - i];
                    accA[i] += h * g;             // 2x v_pk_fma_f32
                    acc4[i] = fmaf(g, hb, acc4[i]);
                }
            }
            sl = (sl + 1 == WIN) ? 0 : sl + 1;
        }
#pragma unroll
        for (int i = 0; i < 8; ++i) {
            const int gr2 = R0 + rr0 + i;
            const int gc  = C0 + c;
            if (gr2 < H && gc < W) {
                const float mu1 = accA[i].x, mu2 = accA[i].y;
                const float mu1s = mu1*mu1, mu2s = mu2*mu2, m12 = mu1*mu2;
                const float s1  = accA[i].z - mu1s;
                const float s2  = accA[i].w - mu2s;
                const float s12 = acc4[i] - m12;
                const float num = (2.f * m12 + C1) * (2.f * s12 + C2);
                const float den = (mu1s + mu2s + C1) * (s1 + s2 + C2);
                local += num * __builtin_amdgcn_rcpf(den + 1e-8f);
            }
        }
        __syncthreads();   // C: all V reads done; prefetched loads have landed

        // (D) pool store + H conv/write for subtile tt+1
        if (do_ds) {
#pragma unroll
            for (int ii = 0; ii < 2; ++ii) {
                const int i  = t + (ii << 8);
                const int dr = i >> 5, dc = i & 31;
                const int gr2 = (R0 >> 1) + dr, gc2 = (C0 >> 1) + dc;
                if (gr2 < dsH && gc2 < dsW) {
                    const long o = dbase + (long)gr2 * dsRowStride + gc2;
                    dsx[o] = 0.25f*(pa0[ii].x+pa0[ii].y+pa1[ii].x+pa1[ii].y);
                    dsy[o] = 0.25f*(pb0[ii].x+pb0[ii].y+pb1[ii].x+pb1[ii].y);
                }
                if (gr2 < dsH && dc < 8) {        // zero the 8-col pads
                    if (blockIdx.x == 0) {
                        const long o = dbase + (long)gr2 * dsRowStride + (dc - 8);
                        dsx[o] = 0.0f; dsy[o] = 0.0f;
                    }
                    if (blockIdx.x == gridDim.x - 1) {
                        const long o = dbase + (long)gr2 * dsRowStride + (dsW + dc);
                        dsx[o] = 0.0f; dsy[o] = 0.0f;
                    }
                }
            }
        }
        if (tt < NSUB - 1)
            h_conv_write(xv, yv, smA, smB, wslot, hq << 3, G);
        __syncthreads();   // B: new window rows visible

        wslot += 32; if (wslot >= WIN) wslot -= WIN;
        vb    += 32; if (vb    >= WIN) vb    -= WIN;
    }

    // ---- wave reduce -> one atomicAdd per wave into its own cache line ----
#pragma unroll
    for (int off = 32; off > 0; off >>= 1) local += __shfl_down(local, off, 64);
    if ((t & 63) == 0) {
        const int bid = (blockIdx.z * gridDim.y + blockIdx.y) * gridDim.x + blockIdx.x;
        const int slot = ((bid << 2) | (t >> 6)) & (NSLOT - 1);
        atomicAdd(slots + slot * SSTRIDE, local);
    }
}

// ---- old per-tile kernel, kept for levels 2-4 (TH=8) ----
template <int TH>
__global__ __launch_bounds__(256, 2) void ssim_level_kernel(
    const float* __restrict__ x, const float* __restrict__ y,
    long imgStride, int rowStride,
    float* __restrict__ dsx, float* __restrict__ dsy,
    long dsImgStride, int dsRowStride,
    const float* __restrict__ zpad,
    float* __restrict__ slots, int H, int W, int pad, int do_ds)
{
    constexpr int HHALO = TH + 10;
    constexpr int RPT   = TH / 4;

    const float G[11] = {
        0.00102839f, 0.00759877f, 0.03600077f, 0.10936069f, 0.21300539f,
        0.26601173f, 0.21300539f, 0.10936069f, 0.03600077f, 0.00759877f,
        0.00102839f};
    const float C1 = 4.0e-4f;
    const float C2 = 3.6e-3f;

    __shared__ __align__(16) v2f   sm01[HHALO * P2];
    __shared__ __align__(16) v2f   sm23[HHALO * P2];
    __shared__ __align__(16) float sm4 [HHALO * P1];

    const int t   = threadIdx.x;
    const int img = blockIdx.z;
    const int C0  = blockIdx.x * TW;
    const int R0  = blockIdx.y * TH;
    const float* xi = x + (long)img * imgStride;
    const float* yi = y + (long)img * imgStride;

    if (do_ds) {
        const int dsW = W >> 1, dsH = H >> 1;
        const long dbase = (long)img * dsImgStride;
        for (int i = t; i < (TH / 2) * 32; i += 256) {
            const int dr = i >> 5, dc = i & 31;
            const int gr2 = (R0 >> 1) + dr;
            const int gc2 = (C0 >> 1) + dc;
            if (gr2 < dsH && gc2 < dsW) {
                const float* sx = xi + (long)(2 * gr2) * rowStride + 2 * gc2;
                const float* sy = yi + (long)(2 * gr2) * rowStride + 2 * gc2;
                const float2 a0 = *reinterpret_cast<const float2*>(sx);
                const float2 a1 = *reinterpret_cast<const float2*>(sx + rowStride);
                const float2 b0 = *reinterpret_cast<const float2*>(sy);
                const float2 b1 = *reinterpret_cast<const float2*>(sy + rowStride);
                const long o = dbase + (long)gr2 * dsRowStride + gc2;
                dsx[o] = 0.25f * (a0.x + a0.y + a1.x + a1.y);
                dsy[o] = 0.25f * (b0.x + b0.y + b1.x + b1.y);
            }
            if (gr2 < dsH && dc < 8) {
                if (blockIdx.x == 0) {
                    const long o = dbase + (long)gr2 * dsRowStride + (dc - 8);
                    dsx[o] = 0.0f; dsy[o] = 0.0f;
                }
                if (blockIdx.x == gridDim.x - 1) {
                    const long o = dbase + (long)gr2 * dsRowStride + (dsW + dc);
                    dsx[o] = 0.0f; dsy[o] = 0.0f;
                }
            }
        }
    }

    const bool fastp = pad || ((C0 >= 8) && (C0 + TW + 8 <= W));
    for (int s = t; s < HHALO * 8; s += 256) {
        const int r  = s % HHALO;
        const int q  = s / HHALO;
        const int gr = R0 + r - 5;
        const bool rok = ((unsigned)gr < (unsigned)H);
        const int gc0 = C0 + (q << 3) - 8;

        float xv[24], yv[24];
        if (fastp) {
            const float* px = rok ? (xi + (long)gr * rowStride + gc0) : zpad;
            const float* py = rok ? (yi + (long)gr * rowStride + gc0) : zpad;
#pragma unroll
            for (int v = 0; v < 6; ++v) {
                const float4 a = reinterpret_cast<const float4*>(px)[v];
                const float4 b = reinterpret_cast<const float4*>(py)[v];
                xv[4 * v + 0] = a.x; xv[4 * v + 1] = a.y;
                xv[4 * v + 2] = a.z; xv[4 * v + 3] = a.w;
                yv[4 * v + 0] = b.x; yv[4 * v + 1] = b.y;
                yv[4 * v + 2] = b.z; yv[4 * v + 3] = b.w;
            }
        } else {
            const float* xrow = xi + (long)gr * rowStride;
            const float* yrow = yi + (long)gr * rowStride;
#pragma unroll
            for (int k = 3; k < 21; ++k) {
                const int gc = gc0 + k;
                const bool ok = rok && ((unsigned)gc < (unsigned)W);
                xv[k] = ok ? xrow[gc] : 0.0f;
                yv[k] = ok ? yrow[gc] : 0.0f;
            }
        }

        v2f w2[18]; float xy[18];
#pragma unroll
        for (int k = 0; k < 18; ++k) {
            const float a = xv[k + 3], b = yv[k + 3];
            v2f w; w.x = a * a; w.y = b * b;
            w2[k] = w; xy[k] = a * b;
        }

        const int cb = (q << 3);
#pragma unroll
        for (int j = 0; j < 8; ++j) {
            v2f s01 = {0.f, 0.f}, s23 = {0.f, 0.f};
            float s4 = 0.f;
#pragma unroll
            for (int k = 0; k < 11; ++k) {
                const float g = G[k];
                v2f w; w.x = xv[j + k + 3]; w.y = yv[j + k + 3];
                s01 += w * g;
                s23 += w2[j + k] * g;
                s4   = fmaf(g, xy[j + k], s4);
            }
            sm01[r * P2 + cb + j] = s01;
            sm23[r * P2 + cb + j] = s23;
            sm4 [r * P1 + cb + j] = s4;
        }
    }
    __syncthreads();

    const int c   = t & 63;
    const int rr0 = (t >> 6) * RPT;
    v2f acc01[RPT], acc23[RPT];
    float acc4[RPT];
    {
        v2f hv[RPT + 10];
#pragma unroll
        for (int k = 0; k < RPT + 10; ++k) hv[k] = sm01[(rr0 + k) * P2 + c];
#pragma unroll
        for (int i = 0; i < RPT; ++i) {
            v2f a = {0.f, 0.f};
#pragma unroll
            for (int k = 0; k < 11; ++k) a += hv[i + k] * G[k];
            acc01[i] = a;
        }
#pragma unroll
        for (int k = 0; k < RPT + 10; ++k) hv[k] = sm23[(rr0 + k) * P2 + c];
#pragma unroll
        for (int i = 0; i < RPT; ++i) {
            v2f a = {0.f, 0.f};
#pragma unroll
            for (int k = 0; k < 11; ++k) a += hv[i + k] * G[k];
            acc23[i] = a;
        }
    }
    {
        float hs[RPT + 10];
#pragma unroll
        for (int k = 0; k < RPT + 10; ++k) hs[k] = sm4[(rr0 + k) * P1 + c];
#pragma unroll
        for (int i = 0; i < RPT; ++i) {
            float a = 0.f;
#pragma unroll
            for (int k = 0; k < 11; ++k) a = fmaf(G[k], hs[i + k], a);
            acc4[i] = a;
        }
    }

    float local = 0.f;
    const int gc = C0 + c;
#pragma unroll
    for (int i = 0; i < RPT; ++i) {
        const int gr2 = R0 + rr0 + i;
        if (gr2 < H && gc < W) {
            const float mu1 = acc01[i].x, mu2 = acc01[i].y;
            const float mu1s = mu1 * mu1, mu2s = mu2 * mu2, m12 = mu1 * mu2;
            const float s1  = acc23[i].x - mu1s;
            const float s2  = acc23[i].y - mu2s;
            const float s12 = acc4[i] - m12;
            const float num = (2.f * m12 + C1) * (2.f * s12 + C2);
            const float den = (mu1s + mu2s + C1) * (s1 + s2 + C2);
            local += num * __builtin_amdgcn_rcpf(den + 1e-8f);
        }
    }

#pragma unroll
    for (int off = 32; off > 0; off >>= 1) local += __shfl_down(local, off, 64);
    if ((t & 63) == 0) {
        const int bid = (blockIdx.z * gridDim.y + blockIdx.y) * gridDim.x + blockIdx.x;
        const int slot = ((bid << 2) | (t >> 6)) & (NSLOT - 1);
        atomicAdd(slots + slot * SSTRIDE, local);
    }
}

__global__ void finalize_kernel(const float* __restrict__ slots,
                                float* __restrict__ out)
{
    const int t = threadIdx.x;
    const float w[5] = {0.0448f, 0.2856f, 0.3001f, 0.2363f, 0.1333f};
    const float wsum = w[0] + w[1] + w[2] + w[3] + w[4];
    float acc = 0.f;
#pragma unroll
    for (int lvl = 0; lvl < 5; ++lvl) {
        const int d = 512 >> lvl;
        const float cnt = (float)NIMG * (float)d * (float)d;
        acc += (w[lvl] / wsum) / cnt * slots[(lvl * NSLOT + t) * SSTRIDE];
    }
#pragma unroll
    for (int off = 32; off > 0; off >>= 1) acc += __shfl_down(acc, off, 64);
    __shared__ float p[4];
    if ((t & 63) == 0) p[t >> 6] = acc;
    __syncthreads();
    if (t == 0) out[0] = 1.0f - (p[0] + p[1] + p[2] + p[3]);
}

extern "C" void kernel_launch(void* const* d_in, const int* in_sizes, int n_in,
                              void* d_out, int out_size, void* d_ws, size_t ws_size,
                              hipStream_t stream)
{
    const float* pred = (const float*)d_in[0];
    const float* targ = (const float*)d_in[1];
    float* out = (float*)d_out;
    float* ws  = (float*)d_ws;

    // padded pyramid: stride = W + 16 (8 zero cols each side)
    const long S1 = 256L * 272, S2 = 128L * 144, S3 = 64L * 80, S4 = 32L * 48;

    float* slots = ws;                           // 5 * 256 * 16 floats (80 KB)
    float* zpad  = slots + 5 * NSLOT * SSTRIDE;  // 640 zero floats
    float* x1 = zpad + 640;
    float* y1 = x1 + NIMG * S1;
    float* x2 = y1 + NIMG * S1;
    float* y2 = x2 + NIMG * S2;
    float* x3 = y2 + NIMG * S2;
    float* y3 = x3 + NIMG * S3;
    float* x4 = y3 + NIMG * S3;
    float* y4 = x4 + NIMG * S4;

    hipMemsetAsync(ws, 0, (size_t)(5 * NSLOT * SSTRIDE + 640) * sizeof(float), stream);

    // level 0: rolling strips 64x128, NSUB=4 -> (8,4,48) = 1536 blocks
    { dim3 g(8, 4, NIMG);
      ssim_rolling_kernel<4><<<g, 256, 0, stream>>>(pred, targ, 512L * 512, 512,
          x1 + 8, y1 + 8, S1, 272, zpad, slots + 0 * NSLOT * SSTRIDE, 512, 512, 0, 1); }
    // level 1: rolling strips 64x64, NSUB=2 -> (4,4,48) = 768 blocks
    { dim3 g(4, 4, NIMG);
      ssim_rolling_kernel<2><<<g, 256, 0, stream>>>(x1 + 8, y1 + 8, S1, 272,
          x2 + 8, y2 + 8, S2, 144, zpad, slots + 1 * NSLOT * SSTRIDE, 256, 256, 1, 1); }
    // level 2: TH=8 -> 1,536 blocks
    { dim3 g(2, 16, NIMG);
      ssim_level_kernel<8><<<g, 256, 0, stream>>>(x2 + 8, y2 + 8, S2, 144,
          x3 + 8, y3 + 8, S3, 80, zpad, slots + 2 * NSLOT * SSTRIDE, 128, 128, 1, 1); }
    // level 3: TH=8 -> 384 blocks
    { dim3 g(1, 8, NIMG);
      ssim_level_kernel<8><<<g, 256, 0, stream>>>(x3 + 8, y3 + 8, S3, 80,
          x4 + 8, y4 + 8, S4, 48, zpad, slots + 3 * NSLOT * SSTRIDE, 64, 64, 1, 1); }
    // level 4: TH=8 -> 192 blocks, no downsample
    { dim3 g(1, 4, NIMG);
      ssim_level_kernel<8><<<g, 256, 0, stream>>>(x4 + 8, y4 + 8, S4, 48,
          nullptr, nullptr, 0, 0, zpad, slots + 4 * NSLOT * SSTRIDE, 32, 32, 1, 0); }

    finalize_kernel<<<1, 256, 0, stream>>>(slots, out);
}

// Round 2
// 277.200 us; speedup vs baseline: 1.5114x; 1.5114x over previous
//
#include <hip/hip_runtime.h>

// MS-SSIM loss, 5 levels.
// R12: fix R11's scratch-spill catastrophe. Post-mortem R11: WRITE_SIZE
//   27->393 MB, FETCH 92->282 MB, VALUBusy 15%, VGPR=84. Live set (~126:
//   48 prefetch + 16 pool + 40 acc + addr) exceeded the 128-VGPR occupancy
//   step forced by launch_bounds(256,3) -> compiler spilled the arrays ->
//   scratch-BW-bound (271us ~= 691MB / 2.56TB/s). Fixes:
//   (a) channel-pack (hx, hy, hxx+hyy, hxy) into ONE v4f plane -- SSIM only
//       needs sig1+sig2, never separately. smB gone: LDS 54272->43008 B,
//       V-phase = 18 ds_read_b128 + 2 pk-fma/tap, acc 40->32 regs.
//   (b) pool loads issued AFTER v_phase (cover = epilogue+barrier+h_conv;
//       rows L2-resident from h_loads) -> 16 pool regs off the k-loop peak.
//   (c) peeled tail, xv/yv inside loop body, unconditional h_load (SROA-
//       friendly), launch_bounds(256,2): cap 256, no forced spill; LDS
//       still gives 3 blocks/CU when VGPR<=128. Peak live est ~108.
// Carried (counter-verified): rolling 42-row window w/ 32-new-rows/subtile
// (halo 1.31x->1.08x); prefetch a full V-phase ahead; XOR-swizzled v4f LDS
// (R11: conflicts 860K->553K); spread atomics 1 line/slot; padded pyramid
// + zpad row-select; fastp block-uniform edge path; tiny memset.

#define TW 64
#define NIMG 48
#define WIN 42                 // rolling window rows (32 + 10)
#define PQ  64                 // v4f pitch, packed (hx,hy,hxx+hyy,hxy), XOR-swizzled
#define P2 63                  // old per-tile kernel: float2 pitch
#define P1 62                  // old per-tile kernel: float pitch
#define NSLOT 256
#define SSTRIDE 16             // 64 B between slots -> 1 cache line each

typedef float v2f __attribute__((ext_vector_type(2)));
typedef float v4f __attribute__((ext_vector_type(4)));

__device__ __forceinline__ void h_load(
    const float* __restrict__ xi, const float* __restrict__ yi,
    const float* __restrict__ zpad, int gr, int gc0, int H, int W,
    bool fastp, int rowStride, float* xv, float* yv)
{
    const bool rok = ((unsigned)gr < (unsigned)H);
    if (fastp) {
        const float* px = rok ? (xi + (long)gr * rowStride + gc0) : zpad;
        const float* py = rok ? (yi + (long)gr * rowStride + gc0) : zpad;
#pragma unroll
        for (int v = 0; v < 6; ++v) {
            const float4 a = reinterpret_cast<const float4*>(px)[v];
            const float4 b = reinterpret_cast<const float4*>(py)[v];
            xv[4*v+0]=a.x; xv[4*v+1]=a.y; xv[4*v+2]=a.z; xv[4*v+3]=a.w;
            yv[4*v+0]=b.x; yv[4*v+1]=b.y; yv[4*v+2]=b.z; yv[4*v+3]=b.w;
        }
    } else {
        const float* xrow = xi + (long)gr * rowStride;
        const float* yrow = yi + (long)gr * rowStride;
#pragma unroll
        for (int k = 3; k < 21; ++k) {
            const int gc = gc0 + k;
            const bool ok = rok && ((unsigned)gc < (unsigned)W);
            xv[k] = ok ? xrow[gc] : 0.0f;
            yv[k] = ok ? yrow[gc] : 0.0f;
        }
    }
}

// H-conv 8 output cols, packed channels (x, y, x^2+y^2, xy) -> one b128/col
__device__ __forceinline__ void h_conv_write(
    const float* xv, const float* yv, v4f* smA, int slot, int cb,
    const float* G)
{
    v4f s[8];
#pragma unroll
    for (int j = 0; j < 8; ++j) s[j] = {0.f, 0.f, 0.f, 0.f};
    // scatter-accumulate: tap position m feeds outputs j in [m-10, m]
#pragma unroll
    for (int m = 0; m < 18; ++m) {
        const float a = xv[m+3], b = yv[m+3];
        v4f w; w.x = a; w.y = b; w.z = a*a + b*b; w.w = a*b;
#pragma unroll
        for (int j = 0; j < 8; ++j) {
            if (j <= m && m - j <= 10) {
                s[j] += w * G[m - j];              // 2x v_pk_fma_f32
            }
        }
    }
    const int u = slot & 31;
#pragma unroll
    for (int j = 0; j < 8; ++j)
        smA[slot * PQ + ((cb + j) ^ u)] = s[j];    // ds_write_b128
}

// V-conv 8 output rows at col c + SSIM epilogue; returns partial sum
__device__ __forceinline__ float v_phase(
    const v4f* smA, int vb, int c, int rr0, int R0, int C0, int H, int W,
    const float* G)
{
    const float C1 = 4.0e-4f;
    const float C2 = 3.6e-3f;
    v4f acc[8];
#pragma unroll
    for (int i = 0; i < 8; ++i) acc[i] = {0.f, 0.f, 0.f, 0.f};
    int sl = __builtin_amdgcn_readfirstlane(vb);   // wave-uniform -> SGPR
#pragma unroll
    for (int k = 0; k < 18; ++k) {
        const v4f h = smA[sl * PQ + (c ^ (sl & 31))];  // ds_read_b128
#pragma unroll
        for (int i = 0; i < 8; ++i) {
            if (i <= k && k - i <= 10) {
                acc[i] += h * G[k - i];            // 2x v_pk_fma_f32
            }
        }
        sl = (sl + 1 == WIN) ? 0 : sl + 1;
    }
    float local = 0.f;
    const int gc = C0 + c;
#pragma unroll
    for (int i = 0; i < 8; ++i) {
        const int gr2 = R0 + rr0 + i;
        if (gr2 < H && gc < W) {
            const float mu1 = acc[i].x, mu2 = acc[i].y;
            const float mu1s = mu1*mu1, mu2s = mu2*mu2, m12 = mu1*mu2;
            const float ssum = acc[i].z - mu1s - mu2s;   // sig1+sig2
            const float s12  = acc[i].w - m12;
            const float num = (2.f * m12 + C1) * (2.f * s12 + C2);
            const float den = (mu1s + mu2s + C1) * (ssum + C2);
            local += num * __builtin_amdgcn_rcpf(den + 1e-8f);
        }
    }
    return local;
}

template <int NSUB>
__global__ __launch_bounds__(256, 2) void ssim_rolling_kernel(
    const float* __restrict__ x, const float* __restrict__ y,
    long imgStride, int rowStride,
    float* __restrict__ dsx, float* __restrict__ dsy,
    long dsImgStride, int dsRowStride,
    const float* __restrict__ zpad,
    float* __restrict__ slots, int H, int W, int pad, int do_ds)
{
    const float G[11] = {
        0.00102839f, 0.00759877f, 0.03600077f, 0.10936069f, 0.21300539f,
        0.26601173f, 0.21300539f, 0.10936069f, 0.03600077f, 0.00759877f,
        0.00102839f};

    __shared__ __align__(16) v4f smA[WIN * PQ];   // 43008 B

    const int t   = threadIdx.x;
    const int img = blockIdx.z;
    const int C0  = blockIdx.x * TW;
    const int S0  = blockIdx.y * (NSUB * 32);     // strip start row
    const float* xi = x + (long)img * imgStride;
    const float* yi = y + (long)img * imgStride;
    const bool fastp = pad || ((C0 >= 8) && (C0 + TW + 8 <= W));

    // ---- prologue: fill window slots 0..41 with h-rows [S0-5, S0+37) ----
    for (int s = t; s < WIN * 8; s += 256) {
        const int r = s % WIN, q = s / WIN;
        float pxv[24], pyv[24];
        h_load(xi, yi, zpad, S0 + r - 5, C0 + (q << 3) - 8, H, W, fastp,
               rowStride, pxv, pyv);
        h_conv_write(pxv, pyv, smA, r, q << 3, G);
    }
    __syncthreads();

    const int c    = t & 63;
    const int rr0  = (t >> 6) * 8;                // wave-uniform
    const int hr   = t & 31, hq = t >> 5;
    const int hgc0 = C0 + (hq << 3) - 8;
    int wslot = hr;                               // H-write slot
    int vb    = rr0;                              // V base slot
    float local = 0.f;
    const int dsW = W >> 1, dsH = H >> 1;
    const long dbase = (long)img * dsImgStride;

    for (int tt = 0; tt < NSUB - 1; ++tt) {
        const int R0 = S0 + 32 * tt;

        // (A) issue next subtile's H loads -- consumed after barrier C
        float xv[24], yv[24];
        h_load(xi, yi, zpad, R0 + 37 + hr, hgc0, H, W, fastp, rowStride,
               xv, yv);

        // (C) V phase + SSIM epilogue (covers the H-load latency)
        local += v_phase(smA, vb, c, rr0, R0, C0, H, W, G);

        // (B) pool loads (cover = epilogue tail + barrier + h_conv_write;
        //     rows are L2-resident from h_loads)
        float2 pa0[2], pa1[2], pb0[2], pb1[2];
        if (do_ds) {
#pragma unroll
            for (int ii = 0; ii < 2; ++ii) {
                const int i  = t + (ii << 8);
                const int dr = i >> 5, dc = i & 31;
                const int gr2 = (R0 >> 1) + dr, gc2 = (C0 >> 1) + dc;
                if (gr2 < dsH && gc2 < dsW) {
                    const float* sx = xi + (long)(2*gr2) * rowStride + 2*gc2;
                    const float* sy = yi + (long)(2*gr2) * rowStride + 2*gc2;
                    pa0[ii] = *reinterpret_cast<const float2*>(sx);
                    pa1[ii] = *reinterpret_cast<const float2*>(sx + rowStride);
                    pb0[ii] = *reinterpret_cast<const float2*>(sy);
                    pb1[ii] = *reinterpret_cast<const float2*>(sy + rowStride);
                }
            }
        }
        __syncthreads();   // C: all V reads done; prefetched loads landed

        // (D) window update (xv/yv die here), then pool store
        h_conv_write(xv, yv, smA, wslot, hq << 3, G);
        if (do_ds) {
#pragma unroll
            for (int ii = 0; ii < 2; ++ii) {
                const int i  = t + (ii << 8);
                const int dr = i >> 5, dc = i & 31;
                const int gr2 = (R0 >> 1) + dr, gc2 = (C0 >> 1) + dc;
                if (gr2 < dsH && gc2 < dsW) {
                    const long o = dbase + (long)gr2 * dsRowStride + gc2;
                    dsx[o] = 0.25f*(pa0[ii].x+pa0[ii].y+pa1[ii].x+pa1[ii].y);
                    dsy[o] = 0.25f*(pb0[ii].x+pb0[ii].y+pb1[ii].x+pb1[ii].y);
                }
                if (gr2 < dsH && dc < 8) {        // zero the 8-col pads
                    if (blockIdx.x == 0) {
                        const long o = dbase + (long)gr2 * dsRowStride + (dc - 8);
                        dsx[o] = 0.0f; dsy[o] = 0.0f;
                    }
                    if (blockIdx.x == gridDim.x - 1) {
                        const long o = dbase + (long)gr2 * dsRowStride + (dsW + dc);
                        dsx[o] = 0.0f; dsy[o] = 0.0f;
                    }
                }
            }
        }
        __syncthreads();   // B: new window rows visible

        wslot += 32; if (wslot >= WIN) wslot -= WIN;
        vb    += 32; if (vb    >= WIN) vb    -= WIN;
    }

    // ---- peeled tail subtile: no prefetch, no window update ----
    {
        const int R0 = S0 + 32 * (NSUB - 1);
        float2 pa0[2], pa1[2], pb0[2], pb1[2];
        if (do_ds) {       // issue pool loads first; V phase covers them
#pragma unroll
            for (int ii = 0; ii < 2; ++ii) {
                const int i  = t + (ii << 8);
                const int dr = i >> 5, dc = i & 31;
                const int gr2 = (R0 >> 1) + dr, gc2 = (C0 >> 1) + dc;
                if (gr2 < dsH && gc2 < dsW) {
                    const float* sx = xi + (long)(2*gr2) * rowStride + 2*gc2;
                    const float* sy = yi + (long)(2*gr2) * rowStride + 2*gc2;
                    pa0[ii] = *reinterpret_cast<const float2*>(sx);
                    pa1[ii] = *reinterpret_cast<const float2*>(sx + rowStride);
                    pb0[ii] = *reinterpret_cast<const float2*>(sy);
                    pb1[ii] = *reinterpret_cast<const float2*>(sy + rowStride);
                }
            }
        }
        local += v_phase(smA, vb, c, rr0, R0, C0, H, W, G);
        if (do_ds) {
#pragma unroll
            for (int ii = 0; ii < 2; ++ii) {
                const int i  = t + (ii << 8);
                const int dr = i >> 5, dc = i & 31;
                const int gr2 = (R0 >> 1) + dr, gc2 = (C0 >> 1) + dc;
                if (gr2 < dsH && gc2 < dsW) {
                    const long o = dbase + (long)gr2 * dsRowStride + gc2;
                    dsx[o] = 0.25f*(pa0[ii].x+pa0[ii].y+pa1[ii].x+pa1[ii].y);
                    dsy[o] = 0.25f*(pb0[ii].x+pb0[ii].y+pb1[ii].x+pb1[ii].y);
                }
                if (gr2 < dsH && dc < 8) {
                    if (blockIdx.x == 0) {
                        const long o = dbase + (long)gr2 * dsRowStride + (dc - 8);
                        dsx[o] = 0.0f; dsy[o] = 0.0f;
                    }
                    if (blockIdx.x == gridDim.x - 1) {
                        const long o = dbase + (long)gr2 * dsRowStride + (dsW + dc);
                        dsx[o] = 0.0f; dsy[o] = 0.0f;
                    }
                }
            }
        }
    }

    // ---- wave reduce -> one atomicAdd per wave into its own cache line ----
#pragma unroll
    for (int off = 32; off > 0; off >>= 1) local += __shfl_down(local, off, 64);
    if ((t & 63) == 0) {
        const int bid = (blockIdx.z * gridDim.y + blockIdx.y) * gridDim.x + blockIdx.x;
        const int slot = ((bid << 2) | (t >> 6)) & (NSLOT - 1);
        atomicAdd(slots + slot * SSTRIDE, local);
    }
}

// ---- old per-tile kernel, kept for levels 2-4 (TH=8) ----
template <int TH>
__global__ __launch_bounds__(256, 2) void ssim_level_kernel(
    const float* __restrict__ x, const float* __restrict__ y,
    long imgStride, int rowStride,
    float* __restrict__ dsx, float* __restrict__ dsy,
    long dsImgStride, int dsRowStride,
    const float* __restrict__ zpad,
    float* __restrict__ slots, int H, int W, int pad, int do_ds)
{
    constexpr int HHALO = TH + 10;
    constexpr int RPT   = TH / 4;

    const float G[11] = {
        0.00102839f, 0.00759877f, 0.03600077f, 0.10936069f, 0.21300539f,
        0.26601173f, 0.21300539f, 0.10936069f, 0.03600077f, 0.00759877f,
        0.00102839f};
    const float C1 = 4.0e-4f;
    const float C2 = 3.6e-3f;

    __shared__ __align__(16) v2f   sm01[HHALO * P2];
    __shared__ __align__(16) v2f   sm23[HHALO * P2];
    __shared__ __align__(16) float sm4 [HHALO * P1];

    const int t   = threadIdx.x;
    const int img = blockIdx.z;
    const int C0  = blockIdx.x * TW;
    const int R0  = blockIdx.y * TH;
    const float* xi = x + (long)img * imgStride;
    const float* yi = y + (long)img * imgStride;

    if (do_ds) {
        const int dsW = W >> 1, dsH = H >> 1;
        const long dbase = (long)img * dsImgStride;
        for (int i = t; i < (TH / 2) * 32; i += 256) {
            const int dr = i >> 5, dc = i & 31;
            const int gr2 = (R0 >> 1) + dr;
            const int gc2 = (C0 >> 1) + dc;
            if (gr2 < dsH && gc2 < dsW) {
                const float* sx = xi + (long)(2 * gr2) * rowStride + 2 * gc2;
                const float* sy = yi + (long)(2 * gr2) * rowStride + 2 * gc2;
                const float2 a0 = *reinterpret_cast<const float2*>(sx);
                const float2 a1 = *reinterpret_cast<const float2*>(sx + rowStride);
                const float2 b0 = *reinterpret_cast<const float2*>(sy);
                const float2 b1 = *reinterpret_cast<const float2*>(sy + rowStride);
                const long o = dbase + (long)gr2 * dsRowStride + gc2;
                dsx[o] = 0.25f * (a0.x + a0.y + a1.x + a1.y);
                dsy[o] = 0.25f * (b0.x + b0.y + b1.x + b1.y);
            }
            if (gr2 < dsH && dc < 8) {
                if (blockIdx.x == 0) {
                    const long o = dbase + (long)gr2 * dsRowStride + (dc - 8);
                    dsx[o] = 0.0f; dsy[o] = 0.0f;
                }
                if (blockIdx.x == gridDim.x - 1) {
                    const long o = dbase + (long)gr2 * dsRowStride + (dsW + dc);
                    dsx[o] = 0.0f; dsy[o] = 0.0f;
                }
            }
        }
    }

    const bool fastp = pad || ((C0 >= 8) && (C0 + TW + 8 <= W));
    for (int s = t; s < HHALO * 8; s += 256) {
        const int r  = s % HHALO;
        const int q  = s / HHALO;
        const int gr = R0 + r - 5;
        const bool rok = ((unsigned)gr < (unsigned)H);
        const int gc0 = C0 + (q << 3) - 8;

        float xv[24], yv[24];
        if (fastp) {
            const float* px = rok ? (xi + (long)gr * rowStride + gc0) : zpad;
            const float* py = rok ? (yi + (long)gr * rowStride + gc0) : zpad;
#pragma unroll
            for (int v = 0; v < 6; ++v) {
                const float4 a = reinterpret_cast<const float4*>(px)[v];
                const float4 b = reinterpret_cast<const float4*>(py)[v];
                xv[4 * v + 0] = a.x; xv[4 * v + 1] = a.y;
                xv[4 * v + 2] = a.z; xv[4 * v + 3] = a.w;
                yv[4 * v + 0] = b.x; yv[4 * v + 1] = b.y;
                yv[4 * v + 2] = b.z; yv[4 * v + 3] = b.w;
            }
        } else {
            const float* xrow = xi + (long)gr * rowStride;
            const float* yrow = yi + (long)gr * rowStride;
#pragma unroll
            for (int k = 3; k < 21; ++k) {
                const int gc = gc0 + k;
                const bool ok = rok && ((unsigned)gc < (unsigned)W);
                xv[k] = ok ? xrow[gc] : 0.0f;
                yv[k] = ok ? yrow[gc] : 0.0f;
            }
        }

        v2f w2[18]; float xy[18];
#pragma unroll
        for (int k = 0; k < 18; ++k) {
            const float a = xv[k + 3], b = yv[k + 3];
            v2f w; w.x = a * a; w.y = b * b;
            w2[k] = w; xy[k] = a * b;
        }

        const int cb = (q << 3);
#pragma unroll
        for (int j = 0; j < 8; ++j) {
            v2f s01 = {0.f, 0.f}, s23 = {0.f, 0.f};
            float s4 = 0.f;
#pragma unroll
            for (int k = 0; k < 11; ++k) {
                const float g = G[k];
                v2f w; w.x = xv[j + k + 3]; w.y = yv[j + k + 3];
                s01 += w * g;
                s23 += w2[j + k] * g;
                s4   = fmaf(g, xy[j + k], s4);
            }
            sm01[r * P2 + cb + j] = s01;
            sm23[r * P2 + cb + j] = s23;
            sm4 [r * P1 + cb + j] = s4;
        }
    }
    __syncthreads();

    const int c   = t & 63;
    const int rr0 = (t >> 6) * RPT;
    v2f acc01[RPT], acc23[RPT];
    float acc4[RPT];
    {
        v2f hv[RPT + 10];
#pragma unroll
        for (int k = 0; k < RPT + 10; ++k) hv[k] = sm01[(rr0 + k) * P2 + c];
#pragma unroll
        for (int i = 0; i < RPT; ++i) {
            v2f a = {0.f, 0.f};
#pragma unroll
            for (int k = 0; k < 11; ++k) a += hv[i + k] * G[k];
            acc01[i] = a;
        }
#pragma unroll
        for (int k = 0; k < RPT + 10; ++k) hv[k] = sm23[(rr0 + k) * P2 + c];
#pragma unroll
        for (int i = 0; i < RPT; ++i) {
            v2f a = {0.f, 0.f};
#pragma unroll
            for (int k = 0; k < 11; ++k) a += hv[i + k] * G[k];
            acc23[i] = a;
        }
    }
    {
        float hs[RPT + 10];
#pragma unroll
        for (int k = 0; k < RPT + 10; ++k) hs[k] = sm4[(rr0 + k) * P1 + c];
#pragma unroll
        for (int i = 0; i < RPT; ++i) {
            float a = 0.f;
#pragma unroll
            for (int k = 0; k < 11; ++k) a = fmaf(G[k], hs[i + k], a);
            acc4[i] = a;
        }
    }

    float local = 0.f;
    const int gc = C0 + c;
#pragma unroll
    for (int i = 0; i < RPT; ++i) {
        const int gr2 = R0 + rr0 + i;
        if (gr2 < H && gc < W) {
            const float mu1 = acc01[i].x, mu2 = acc01[i].y;
            const float mu1s = mu1 * mu1, mu2s = mu2 * mu2, m12 = mu1 * mu2;
            const float s1  = acc23[i].x - mu1s;
            const float s2  = acc23[i].y - mu2s;
            const float s12 = acc4[i] - m12;
            const float num = (2.f * m12 + C1) * (2.f * s12 + C2);
            const float den = (mu1s + mu2s + C1) * (s1 + s2 + C2);
            local += num * __builtin_amdgcn_rcpf(den + 1e-8f);
        }
    }

#pragma unroll
    for (int off = 32; off > 0; off >>= 1) local += __shfl_down(local, off, 64);
    if ((t & 63) == 0) {
        const int bid = (blockIdx.z * gridDim.y + blockIdx.y) * gridDim.x + blockIdx.x;
        const int slot = ((bid << 2) | (t >> 6)) & (NSLOT - 1);
        atomicAdd(slots + slot * SSTRIDE, local);
    }
}

__global__ void finalize_kernel(const float* __restrict__ slots,
                                float* __restrict__ out)
{
    const int t = threadIdx.x;
    const float w[5] = {0.0448f, 0.2856f, 0.3001f, 0.2363f, 0.1333f};
    const float wsum = w[0] + w[1] + w[2] + w[3] + w[4];
    float acc = 0.f;
#pragma unroll
    for (int lvl = 0; lvl < 5; ++lvl) {
        const int d = 512 >> lvl;
        const float cnt = (float)NIMG * (float)d * (float)d;
        acc += (w[lvl] / wsum) / cnt * slots[(lvl * NSLOT + t) * SSTRIDE];
    }
#pragma unroll
    for (int off = 32; off > 0; off >>= 1) acc += __shfl_down(acc, off, 64);
    __shared__ float p[4];
    if ((t & 63) == 0) p[t >> 6] = acc;
    __syncthreads();
    if (t == 0) out[0] = 1.0f - (p[0] + p[1] + p[2] + p[3]);
}

extern "C" void kernel_launch(void* const* d_in, const int* in_sizes, int n_in,
                              void* d_out, int out_size, void* d_ws, size_t ws_size,
                              hipStream_t stream)
{
    const float* pred = (const float*)d_in[0];
    const float* targ = (const float*)d_in[1];
    float* out = (float*)d_out;
    float* ws  = (float*)d_ws;

    // padded pyramid: stride = W + 16 (8 zero cols each side)
    const long S1 = 256L * 272, S2 = 128L * 144, S3 = 64L * 80, S4 = 32L * 48;

    float* slots = ws;                           // 5 * 256 * 16 floats (80 KB)
    float* zpad  = slots + 5 * NSLOT * SSTRIDE;  // 640 zero floats
    float* x1 = zpad + 640;
    float* y1 = x1 + NIMG * S1;
    float* x2 = y1 + NIMG * S1;
    float* y2 = x2 + NIMG * S2;
    float* x3 = y2 + NIMG * S2;
    float* y3 = x3 + NIMG * S3;
    float* x4 = y3 + NIMG * S3;
    float* y4 = x4 + NIMG * S4;

    hipMemsetAsync(ws, 0, (size_t)(5 * NSLOT * SSTRIDE + 640) * sizeof(float), stream);

    // level 0: rolling strips 64x128, NSUB=4 -> (8,4,48) = 1536 blocks
    { dim3 g(8, 4, NIMG);
      ssim_rolling_kernel<4><<<g, 256, 0, stream>>>(pred, targ, 512L * 512, 512,
          x1 + 8, y1 + 8, S1, 272, zpad, slots + 0 * NSLOT * SSTRIDE, 512, 512, 0, 1); }
    // level 1: rolling strips 64x64, NSUB=2 -> (4,4,48) = 768 blocks
    { dim3 g(4, 4, NIMG);
      ssim_rolling_kernel<2><<<g, 256, 0, stream>>>(x1 + 8, y1 + 8, S1, 272,
          x2 + 8, y2 + 8, S2, 144, zpad, slots + 1 * NSLOT * SSTRIDE, 256, 256, 1, 1); }
    // level 2: TH=8 -> 1,536 blocks
    { dim3 g(2, 16, NIMG);
      ssim_level_kernel<8><<<g, 256, 0, stream>>>(x2 + 8, y2 + 8, S2, 144,
          x3 + 8, y3 + 8, S3, 80, zpad, slots + 2 * NSLOT * SSTRIDE, 128, 128, 1, 1); }
    // level 3: TH=8 -> 384 blocks
    { dim3 g(1, 8, NIMG);
      ssim_level_kernel<8><<<g, 256, 0, stream>>>(x3 + 8, y3 + 8, S3, 80,
          x4 + 8, y4 + 8, S4, 48, zpad, slots + 3 * NSLOT * SSTRIDE, 64, 64, 1, 1); }
    // level 4: TH=8 -> 192 blocks, no downsample
    { dim3 g(1, 4, NIMG);
      ssim_level_kernel<8><<<g, 256, 0, stream>>>(x4 + 8, y4 + 8, S4, 48,
          nullptr, nullptr, 0, 0, zpad, slots + 4 * NSLOT * SSTRIDE, 32, 32, 1, 0); }

    finalize_kernel<<<1, 256, 0, stream>>>(slots, out);
}

// Round 3
// 267.556 us; speedup vs baseline: 1.5659x; 1.0360x over previous
//
#include <hip/hip_runtime.h>

// MS-SSIM loss, 5 levels.
// R13: occupancy geometry. Post-mortem R12: spill fixed (WRITE 393->35MB)
//   but dur only 271->150us. Occupancy 15.2% = ~1.2 blocks/CU resident
//   (LDS 43KB caps at 3/CU; ragged fill) -> ~1.2 waves/SIMD -> zero
//   latency hiding; VALUBusy 22%, all ds_read chains + barrier vmcnt(0)
//   drains fully exposed. Fix: halve tile width. TW=32, 128-thread
//   blocks (2 waves), WIN=42 -> LDS 21504 B -> 7 blocks/CU = 14 waves
//   (43.75% ceiling); L0 grid 3072, L1 1536 so residency actually fills.
//   Cost: horiz halo 1.25->1.5x (FETCH +~25MB ~ +4us) -- cheap vs stall
//   reclaim. vb no longer wave-uniform (wave spans 2 row-groups): drop
//   readfirstlane, per-lane slot arithmetic. Same 5-bit XOR swizzle
//   stays a full-bank permutation for both H-write and V-read.
// Carried (counter-verified): channel-packed (hx,hy,hxx+hyy,hxy) v4f
// plane; rolling 42-row window, 32 new rows/subtile (halo 1.08x vert);
// prefetch a full V-phase ahead; pool loads after V; spread atomics;
// padded pyramid + zpad row-select; fastp block-uniform edge path.

#define TW 32
#define NTHR 128
#define NIMG 48
#define WIN 42                 // rolling window rows (32 + 10)
#define PQ  32                 // v4f pitch, packed (hx,hy,hxx+hyy,hxy), XOR-swizzled
#define P2 63                  // old per-tile kernel: float2 pitch
#define P1 62                  // old per-tile kernel: float pitch
#define NSLOT 256
#define SSTRIDE 16             // 64 B between slots -> 1 cache line each

typedef float v2f __attribute__((ext_vector_type(2)));
typedef float v4f __attribute__((ext_vector_type(4)));

__device__ __forceinline__ void h_load(
    const float* __restrict__ xi, const float* __restrict__ yi,
    const float* __restrict__ zpad, int gr, int gc0, int H, int W,
    bool fastp, int rowStride, float* xv, float* yv)
{
    const bool rok = ((unsigned)gr < (unsigned)H);
    if (fastp) {
        const float* px = rok ? (xi + (long)gr * rowStride + gc0) : zpad;
        const float* py = rok ? (yi + (long)gr * rowStride + gc0) : zpad;
#pragma unroll
        for (int v = 0; v < 6; ++v) {
            const float4 a = reinterpret_cast<const float4*>(px)[v];
            const float4 b = reinterpret_cast<const float4*>(py)[v];
            xv[4*v+0]=a.x; xv[4*v+1]=a.y; xv[4*v+2]=a.z; xv[4*v+3]=a.w;
            yv[4*v+0]=b.x; yv[4*v+1]=b.y; yv[4*v+2]=b.z; yv[4*v+3]=b.w;
        }
    } else {
        const float* xrow = xi + (long)gr * rowStride;
        const float* yrow = yi + (long)gr * rowStride;
#pragma unroll
        for (int k = 3; k < 21; ++k) {
            const int gc = gc0 + k;
            const bool ok = rok && ((unsigned)gc < (unsigned)W);
            xv[k] = ok ? xrow[gc] : 0.0f;
            yv[k] = ok ? yrow[gc] : 0.0f;
        }
    }
}

// H-conv 8 output cols, packed channels (x, y, x^2+y^2, xy) -> one b128/col
__device__ __forceinline__ void h_conv_write(
    const float* xv, const float* yv, v4f* smA, int slot, int cb,
    const float* G)
{
    v4f s[8];
#pragma unroll
    for (int j = 0; j < 8; ++j) s[j] = {0.f, 0.f, 0.f, 0.f};
    // scatter-accumulate: tap position m feeds outputs j in [m-10, m]
#pragma unroll
    for (int m = 0; m < 18; ++m) {
        const float a = xv[m+3], b = yv[m+3];
        v4f w; w.x = a; w.y = b; w.z = a*a + b*b; w.w = a*b;
#pragma unroll
        for (int j = 0; j < 8; ++j) {
            if (j <= m && m - j <= 10) {
                s[j] += w * G[m - j];              // 2x v_pk_fma_f32
            }
        }
    }
    const int u = slot & 31;
#pragma unroll
    for (int j = 0; j < 8; ++j)
        smA[slot * PQ + ((cb + j) ^ u)] = s[j];    // ds_write_b128
}

// V-conv 8 output rows at col c + SSIM epilogue; returns partial sum.
// vb is per-lane (wave spans two row-groups at 128 threads).
__device__ __forceinline__ float v_phase(
    const v4f* smA, int vb, int c, int rr0, int R0, int C0, int H, int W,
    const float* G)
{
    const float C1 = 4.0e-4f;
    const float C2 = 3.6e-3f;
    v4f acc[8];
#pragma unroll
    for (int i = 0; i < 8; ++i) acc[i] = {0.f, 0.f, 0.f, 0.f};
    int sl = vb;
#pragma unroll
    for (int k = 0; k < 18; ++k) {
        const v4f h = smA[sl * PQ + (c ^ (sl & 31))];  // ds_read_b128
#pragma unroll
        for (int i = 0; i < 8; ++i) {
            if (i <= k && k - i <= 10) {
                acc[i] += h * G[k - i];            // 2x v_pk_fma_f32
            }
        }
        sl = (sl + 1 == WIN) ? 0 : sl + 1;
    }
    float local = 0.f;
    const int gc = C0 + c;
#pragma unroll
    for (int i = 0; i < 8; ++i) {
        const int gr2 = R0 + rr0 + i;
        if (gr2 < H && gc < W) {
            const float mu1 = acc[i].x, mu2 = acc[i].y;
            const float mu1s = mu1*mu1, mu2s = mu2*mu2, m12 = mu1*mu2;
            const float ssum = acc[i].z - mu1s - mu2s;   // sig1+sig2
            const float s12  = acc[i].w - m12;
            const float num = (2.f * m12 + C1) * (2.f * s12 + C2);
            const float den = (mu1s + mu2s + C1) * (ssum + C2);
            local += num * __builtin_amdgcn_rcpf(den + 1e-8f);
        }
    }
    return local;
}

template <int NSUB>
__global__ __launch_bounds__(NTHR, 2) void ssim_rolling_kernel(
    const float* __restrict__ x, const float* __restrict__ y,
    long imgStride, int rowStride,
    float* __restrict__ dsx, float* __restrict__ dsy,
    long dsImgStride, int dsRowStride,
    const float* __restrict__ zpad,
    float* __restrict__ slots, int H, int W, int pad, int do_ds)
{
    const float G[11] = {
        0.00102839f, 0.00759877f, 0.03600077f, 0.10936069f, 0.21300539f,
        0.26601173f, 0.21300539f, 0.10936069f, 0.03600077f, 0.00759877f,
        0.00102839f};

    __shared__ __align__(16) v4f smA[WIN * PQ];   // 21504 B -> 7 blocks/CU

    const int t   = threadIdx.x;
    const int img = blockIdx.z;
    const int C0  = blockIdx.x * TW;
    const int S0  = blockIdx.y * (NSUB * 32);     // strip start row
    const float* xi = x + (long)img * imgStride;
    const float* yi = y + (long)img * imgStride;
    const bool fastp = pad || ((C0 >= 8) && (C0 + TW + 8 <= W));

    // ---- prologue: fill window slots 0..41 with h-rows [S0-5, S0+37) ----
    for (int s = t; s < WIN * 4; s += NTHR) {
        const int r = s % WIN, q = s / WIN;
        float pxv[24], pyv[24];
        h_load(xi, yi, zpad, S0 + r - 5, C0 + (q << 3) - 8, H, W, fastp,
               rowStride, pxv, pyv);
        h_conv_write(pxv, pyv, smA, r, q << 3, G);
    }
    __syncthreads();

    const int c    = t & 31;
    const int rr0  = (t >> 5) * 8;                // per-lane (2 groups/wave)
    const int hr   = t & 31, hq = t >> 5;         // 32 rows x 4 octets
    const int hgc0 = C0 + (hq << 3) - 8;
    int wslot = hr;                               // H-write slot
    int vb    = rr0;                              // V base slot
    float local = 0.f;
    const int dsW = W >> 1, dsH = H >> 1;
    const long dbase = (long)img * dsImgStride;

    for (int tt = 0; tt < NSUB - 1; ++tt) {
        const int R0 = S0 + 32 * tt;

        // (A) issue next subtile's H loads -- consumed after barrier C
        float xv[24], yv[24];
        h_load(xi, yi, zpad, R0 + 37 + hr, hgc0, H, W, fastp, rowStride,
               xv, yv);

        // (C) V phase + SSIM epilogue (covers the H-load latency)
        local += v_phase(smA, vb, c, rr0, R0, C0, H, W, G);

        // (B) pool loads (cover = epilogue tail + barrier + h_conv_write;
        //     rows are L2-resident from h_loads). 16x16 ds tile, 2/thread.
        float2 pa0[2], pa1[2], pb0[2], pb1[2];
        if (do_ds) {
#pragma unroll
            for (int ii = 0; ii < 2; ++ii) {
                const int i  = t + (ii << 7);
                const int dr = i >> 4, dc = i & 15;
                const int gr2 = (R0 >> 1) + dr, gc2 = (C0 >> 1) + dc;
                if (gr2 < dsH && gc2 < dsW) {
                    const float* sx = xi + (long)(2*gr2) * rowStride + 2*gc2;
                    const float* sy = yi + (long)(2*gr2) * rowStride + 2*gc2;
                    pa0[ii] = *reinterpret_cast<const float2*>(sx);
                    pa1[ii] = *reinterpret_cast<const float2*>(sx + rowStride);
                    pb0[ii] = *reinterpret_cast<const float2*>(sy);
                    pb1[ii] = *reinterpret_cast<const float2*>(sy + rowStride);
                }
            }
        }
        __syncthreads();   // C: all V reads done; prefetched loads landed

        // (D) window update (xv/yv die here), then pool store
        h_conv_write(xv, yv, smA, wslot, hq << 3, G);
        if (do_ds) {
#pragma unroll
            for (int ii = 0; ii < 2; ++ii) {
                const int i  = t + (ii << 7);
                const int dr = i >> 4, dc = i & 15;
                const int gr2 = (R0 >> 1) + dr, gc2 = (C0 >> 1) + dc;
                if (gr2 < dsH && gc2 < dsW) {
                    const long o = dbase + (long)gr2 * dsRowStride + gc2;
                    dsx[o] = 0.25f*(pa0[ii].x+pa0[ii].y+pa1[ii].x+pa1[ii].y);
                    dsy[o] = 0.25f*(pb0[ii].x+pb0[ii].y+pb1[ii].x+pb1[ii].y);
                }
                if (gr2 < dsH && dc < 8) {        // zero the 8-col pads
                    if (blockIdx.x == 0) {
                        const long o = dbase + (long)gr2 * dsRowStride + (dc - 8);
                        dsx[o] = 0.0f; dsy[o] = 0.0f;
                    }
                    if (blockIdx.x == gridDim.x - 1) {
                        const long o = dbase + (long)gr2 * dsRowStride + (dsW + dc);
                        dsx[o] = 0.0f; dsy[o] = 0.0f;
                    }
                }
            }
        }
        __syncthreads();   // B: new window rows visible

        wslot += 32; if (wslot >= WIN) wslot -= WIN;
        vb    += 32; if (vb    >= WIN) vb    -= WIN;
    }

    // ---- peeled tail subtile: no prefetch, no window update ----
    {
        const int R0 = S0 + 32 * (NSUB - 1);
        float2 pa0[2], pa1[2], pb0[2], pb1[2];
        if (do_ds) {       // issue pool loads first; V phase covers them
#pragma unroll
            for (int ii = 0; ii < 2; ++ii) {
                const int i  = t + (ii << 7);
                const int dr = i >> 4, dc = i & 15;
                const int gr2 = (R0 >> 1) + dr, gc2 = (C0 >> 1) + dc;
                if (gr2 < dsH && gc2 < dsW) {
                    const float* sx = xi + (long)(2*gr2) * rowStride + 2*gc2;
                    const float* sy = yi + (long)(2*gr2) * rowStride + 2*gc2;
                    pa0[ii] = *reinterpret_cast<const float2*>(sx);
                    pa1[ii] = *reinterpret_cast<const float2*>(sx + rowStride);
                    pb0[ii] = *reinterpret_cast<const float2*>(sy);
                    pb1[ii] = *reinterpret_cast<const float2*>(sy + rowStride);
                }
            }
        }
        local += v_phase(smA, vb, c, rr0, R0, C0, H, W, G);
        if (do_ds) {
#pragma unroll
            for (int ii = 0; ii < 2; ++ii) {
                const int i  = t + (ii << 7);
                const int dr = i >> 4, dc = i & 15;
                const int gr2 = (R0 >> 1) + dr, gc2 = (C0 >> 1) + dc;
                if (gr2 < dsH && gc2 < dsW) {
                    const long o = dbase + (long)gr2 * dsRowStride + gc2;
                    dsx[o] = 0.25f*(pa0[ii].x+pa0[ii].y+pa1[ii].x+pa1[ii].y);
                    dsy[o] = 0.25f*(pb0[ii].x+pb0[ii].y+pb1[ii].x+pb1[ii].y);
                }
                if (gr2 < dsH && dc < 8) {
                    if (blockIdx.x == 0) {
                        const long o = dbase + (long)gr2 * dsRowStride + (dc - 8);
                        dsx[o] = 0.0f; dsy[o] = 0.0f;
                    }
                    if (blockIdx.x == gridDim.x - 1) {
                        const long o = dbase + (long)gr2 * dsRowStride + (dsW + dc);
                        dsx[o] = 0.0f; dsy[o] = 0.0f;
                    }
                }
            }
        }
    }

    // ---- wave reduce -> one atomicAdd per wave into its own cache line ----
#pragma unroll
    for (int off = 32; off > 0; off >>= 1) local += __shfl_down(local, off, 64);
    if ((t & 63) == 0) {
        const int bid = (blockIdx.z * gridDim.y + blockIdx.y) * gridDim.x + blockIdx.x;
        const int slot = ((bid << 2) | (t >> 6)) & (NSLOT - 1);
        atomicAdd(slots + slot * SSTRIDE, local);
    }
}

// ---- old per-tile kernel, kept for levels 2-4 (TH=8) ----
template <int TH>
__global__ __launch_bounds__(256, 2) void ssim_level_kernel(
    const float* __restrict__ x, const float* __restrict__ y,
    long imgStride, int rowStride,
    float* __restrict__ dsx, float* __restrict__ dsy,
    long dsImgStride, int dsRowStride,
    const float* __restrict__ zpad,
    float* __restrict__ slots, int H, int W, int pad, int do_ds)
{
    constexpr int HHALO = TH + 10;
    constexpr int RPT   = TH / 4;

    const float G[11] = {
        0.00102839f, 0.00759877f, 0.03600077f, 0.10936069f, 0.21300539f,
        0.26601173f, 0.21300539f, 0.10936069f, 0.03600077f, 0.00759877f,
        0.00102839f};
    const float C1 = 4.0e-4f;
    const float C2 = 3.6e-3f;

    __shared__ __align__(16) v2f   sm01[HHALO * P2];
    __shared__ __align__(16) v2f   sm23[HHALO * P2];
    __shared__ __align__(16) float sm4 [HHALO * P1];

    const int t   = threadIdx.x;
    const int img = blockIdx.z;
    const int C0  = blockIdx.x * 64;
    const int R0  = blockIdx.y * TH;
    const float* xi = x + (long)img * imgStride;
    const float* yi = y + (long)img * imgStride;

    if (do_ds) {
        const int dsW = W >> 1, dsH = H >> 1;
        const long dbase = (long)img * dsImgStride;
        for (int i = t; i < (TH / 2) * 32; i += 256) {
            const int dr = i >> 5, dc = i & 31;
            const int gr2 = (R0 >> 1) + dr;
            const int gc2 = (C0 >> 1) + dc;
            if (gr2 < dsH && gc2 < dsW) {
                const float* sx = xi + (long)(2 * gr2) * rowStride + 2 * gc2;
                const float* sy = yi + (long)(2 * gr2) * rowStride + 2 * gc2;
                const float2 a0 = *reinterpret_cast<const float2*>(sx);
                const float2 a1 = *reinterpret_cast<const float2*>(sx + rowStride);
                const float2 b0 = *reinterpret_cast<const float2*>(sy);
                const float2 b1 = *reinterpret_cast<const float2*>(sy + rowStride);
                const long o = dbase + (long)gr2 * dsRowStride + gc2;
                dsx[o] = 0.25f * (a0.x + a0.y + a1.x + a1.y);
                dsy[o] = 0.25f * (b0.x + b0.y + b1.x + b1.y);
            }
            if (gr2 < dsH && dc < 8) {
                if (blockIdx.x == 0) {
                    const long o = dbase + (long)gr2 * dsRowStride + (dc - 8);
                    dsx[o] = 0.0f; dsy[o] = 0.0f;
                }
                if (blockIdx.x == gridDim.x - 1) {
                    const long o = dbase + (long)gr2 * dsRowStride + (dsW + dc);
                    dsx[o] = 0.0f; dsy[o] = 0.0f;
                }
            }
        }
    }

    const bool fastp = pad || ((C0 >= 8) && (C0 + 64 + 8 <= W));
    for (int s = t; s < HHALO * 8; s += 256) {
        const int r  = s % HHALO;
        const int q  = s / HHALO;
        const int gr = R0 + r - 5;
        const bool rok = ((unsigned)gr < (unsigned)H);
        const int gc0 = C0 + (q << 3) - 8;

        float xv[24], yv[24];
        if (fastp) {
            const float* px = rok ? (xi + (long)gr * rowStride + gc0) : zpad;
            const float* py = rok ? (yi + (long)gr * rowStride + gc0) : zpad;
#pragma unroll
            for (int v = 0; v < 6; ++v) {
                const float4 a = reinterpret_cast<const float4*>(px)[v];
                const float4 b = reinterpret_cast<const float4*>(py)[v];
                xv[4 * v + 0] = a.x; xv[4 * v + 1] = a.y;
                xv[4 * v + 2] = a.z; xv[4 * v + 3] = a.w;
                yv[4 * v + 0] = b.x; yv[4 * v + 1] = b.y;
                yv[4 * v + 2] = b.z; yv[4 * v + 3] = b.w;
            }
        } else {
            const float* xrow = xi + (long)gr * rowStride;
            const float* yrow = yi + (long)gr * rowStride;
#pragma unroll
            for (int k = 3; k < 21; ++k) {
                const int gc = gc0 + k;
                const bool ok = rok && ((unsigned)gc < (unsigned)W);
                xv[k] = ok ? xrow[gc] : 0.0f;
                yv[k] = ok ? yrow[gc] : 0.0f;
            }
        }

        v2f w2[18]; float xy[18];
#pragma unroll
        for (int k = 0; k < 18; ++k) {
            const float a = xv[k + 3], b = yv[k + 3];
            v2f w; w.x = a * a; w.y = b * b;
            w2[k] = w; xy[k] = a * b;
        }

        const int cb = (q << 3);
#pragma unroll
        for (int j = 0; j < 8; ++j) {
            v2f s01 = {0.f, 0.f}, s23 = {0.f, 0.f};
            float s4 = 0.f;
#pragma unroll
            for (int k = 0; k < 11; ++k) {
                const float g = G[k];
                v2f w; w.x = xv[j + k + 3]; w.y = yv[j + k + 3];
                s01 += w * g;
                s23 += w2[j + k] * g;
                s4   = fmaf(g, xy[j + k], s4);
            }
            sm01[r * P2 + cb + j] = s01;
            sm23[r * P2 + cb + j] = s23;
            sm4 [r * P1 + cb + j] = s4;
        }
    }
    __syncthreads();

    const int c   = t & 63;
    const int rr0 = (t >> 6) * RPT;
    v2f acc01[RPT], acc23[RPT];
    float acc4[RPT];
    {
        v2f hv[RPT + 10];
#pragma unroll
        for (int k = 0; k < RPT + 10; ++k) hv[k] = sm01[(rr0 + k) * P2 + c];
#pragma unroll
        for (int i = 0; i < RPT; ++i) {
            v2f a = {0.f, 0.f};
#pragma unroll
            for (int k = 0; k < 11; ++k) a += hv[i + k] * G[k];
            acc01[i] = a;
        }
#pragma unroll
        for (int k = 0; k < RPT + 10; ++k) hv[k] = sm23[(rr0 + k) * P2 + c];
#pragma unroll
        for (int i = 0; i < RPT; ++i) {
            v2f a = {0.f, 0.f};
#pragma unroll
            for (int k = 0; k < 11; ++k) a += hv[i + k] * G[k];
            acc23[i] = a;
        }
    }
    {
        float hs[RPT + 10];
#pragma unroll
        for (int k = 0; k < RPT + 10; ++k) hs[k] = sm4[(rr0 + k) * P1 + c];
#pragma unroll
        for (int i = 0; i < RPT; ++i) {
            float a = 0.f;
#pragma unroll
            for (int k = 0; k < 11; ++k) a = fmaf(G[k], hs[i + k], a);
            acc4[i] = a;
        }
    }

    float local = 0.f;
    const int gc = C0 + c;
#pragma unroll
    for (int i = 0; i < RPT; ++i) {
        const int gr2 = R0 + rr0 + i;
        if (gr2 < H && gc < W) {
            const float mu1 = acc01[i].x, mu2 = acc01[i].y;
            const float mu1s = mu1 * mu1, mu2s = mu2 * mu2, m12 = mu1 * mu2;
            const float s1  = acc23[i].x - mu1s;
            const float s2  = acc23[i].y - mu2s;
            const float s12 = acc4[i] - m12;
            const float num = (2.f * m12 + C1) * (2.f * s12 + C2);
            const float den = (mu1s + mu2s + C1) * (s1 + s2 + C2);
            local += num * __builtin_amdgcn_rcpf(den + 1e-8f);
        }
    }

#pragma unroll
    for (int off = 32; off > 0; off >>= 1) local += __shfl_down(local, off, 64);
    if ((t & 63) == 0) {
        const int bid = (blockIdx.z * gridDim.y + blockIdx.y) * gridDim.x + blockIdx.x;
        const int slot = ((bid << 2) | (t >> 6)) & (NSLOT - 1);
        atomicAdd(slots + slot * SSTRIDE, local);
    }
}

__global__ void finalize_kernel(const float* __restrict__ slots,
                                float* __restrict__ out)
{
    const int t = threadIdx.x;
    const float w[5] = {0.0448f, 0.2856f, 0.3001f, 0.2363f, 0.1333f};
    const float wsum = w[0] + w[1] + w[2] + w[3] + w[4];
    float acc = 0.f;
#pragma unroll
    for (int lvl = 0; lvl < 5; ++lvl) {
        const int d = 512 >> lvl;
        const float cnt = (float)NIMG * (float)d * (float)d;
        acc += (w[lvl] / wsum) / cnt * slots[(lvl * NSLOT + t) * SSTRIDE];
    }
#pragma unroll
    for (int off = 32; off > 0; off >>= 1) acc += __shfl_down(acc, off, 64);
    __shared__ float p[4];
    if ((t & 63) == 0) p[t >> 6] = acc;
    __syncthreads();
    if (t == 0) out[0] = 1.0f - (p[0] + p[1] + p[2] + p[3]);
}

extern "C" void kernel_launch(void* const* d_in, const int* in_sizes, int n_in,
                              void* d_out, int out_size, void* d_ws, size_t ws_size,
                              hipStream_t stream)
{
    const float* pred = (const float*)d_in[0];
    const float* targ = (const float*)d_in[1];
    float* out = (float*)d_out;
    float* ws  = (float*)d_ws;

    // padded pyramid: stride = W + 16 (8 zero cols each side)
    const long S1 = 256L * 272, S2 = 128L * 144, S3 = 64L * 80, S4 = 32L * 48;

    float* slots = ws;                           // 5 * 256 * 16 floats (80 KB)
    float* zpad  = slots + 5 * NSLOT * SSTRIDE;  // 640 zero floats
    float* x1 = zpad + 640;
    float* y1 = x1 + NIMG * S1;
    float* x2 = y1 + NIMG * S1;
    float* y2 = x2 + NIMG * S2;
    float* x3 = y2 + NIMG * S2;
    float* y3 = x3 + NIMG * S3;
    float* x4 = y3 + NIMG * S3;
    float* y4 = x4 + NIMG * S4;

    hipMemsetAsync(ws, 0, (size_t)(5 * NSLOT * SSTRIDE + 640) * sizeof(float), stream);

    // level 0: rolling strips 32x128, NSUB=4 -> (16,4,48) = 3072 blocks
    { dim3 g(16, 4, NIMG);
      ssim_rolling_kernel<4><<<g, NTHR, 0, stream>>>(pred, targ, 512L * 512, 512,
          x1 + 8, y1 + 8, S1, 272, zpad, slots + 0 * NSLOT * SSTRIDE, 512, 512, 0, 1); }
    // level 1: rolling strips 32x64, NSUB=2 -> (8,4,48) = 1536 blocks
    { dim3 g(8, 4, NIMG);
      ssim_rolling_kernel<2><<<g, NTHR, 0, stream>>>(x1 + 8, y1 + 8, S1, 272,
          x2 + 8, y2 + 8, S2, 144, zpad, slots + 1 * NSLOT * SSTRIDE, 256, 256, 1, 1); }
    // level 2: TH=8 -> 1,536 blocks
    { dim3 g(2, 16, NIMG);
      ssim_level_kernel<8><<<g, 256, 0, stream>>>(x2 + 8, y2 + 8, S2, 144,
          x3 + 8, y3 + 8, S3, 80, zpad, slots + 2 * NSLOT * SSTRIDE, 128, 128, 1, 1); }
    // level 3: TH=8 -> 384 blocks
    { dim3 g(1, 8, NIMG);
      ssim_level_kernel<8><<<g, 256, 0, stream>>>(x3 + 8, y3 + 8, S3, 80,
          x4 + 8, y4 + 8, S4, 48, zpad, slots + 3 * NSLOT * SSTRIDE, 64, 64, 1, 1); }
    // level 4: TH=8 -> 192 blocks, no downsample
    { dim3 g(1, 4, NIMG);
      ssim_level_kernel<8><<<g, 256, 0, stream>>>(x4 + 8, y4 + 8, S4, 48,
          nullptr, nullptr, 0, 0, zpad, slots + 4 * NSLOT * SSTRIDE, 32, 32, 1, 0); }

    finalize_kernel<<<1, 256, 0, stream>>>(slots, out);
}

// Round 4
// 233.466 us; speedup vs baseline: 1.7946x; 1.1460x over previous
//
#include <hip/hip_runtime.h>

// MS-SSIM loss, 5 levels.
// R14: de-serialize the level tree. Post-mortem R13: occupancy theory
//   FAILED (21.5KB LDS / 7-block cap -> occ only 17%, dur 150us again);
//   three different structures all pin at ~150us, occ ~0.4-0.6 of cap.
//   Also: L1-4+finalize = 117us of 267 for 3.3% of pixels -- five
//   serialized latency-bound dispatches. Fix: (a) L0 builds the WHOLE
//   pyramid (x1..x4): pool thread owns 2x2 of x1 (4x4 input, 8 float4
//   loads, same bytes), x2 lane-local, x3/x4 via wave-local shfl quads;
//   edge blocks zero all levels' col pads. (b) Levels 1-4 then have no
//   deps -> ONE merged dispatch (2544 blocks: 1536 L1 + 768 L2 + 192 L3
//   + 48 L4), rolling kernel with pooling stripped (also removes its
//   only uncovered vmcnt drain). Dispatches 6 -> 3. (c) XCD-contiguous
//   tile swizzle (grids % 8 == 0) for halo/pool L2 locality.
//   DISCRIMINATOR: if merged dispatch also shows ~17% occ with 2544
//   blocks resident-eligible, residency cap is not dispatch structure.
// Carried (counter-verified): channel-packed (hx,hy,hxx+hyy,hxy) v4f
// LDS plane, XOR swizzle; rolling 42-row window, 32 new rows/subtile;
// prefetch a full V-phase ahead; TW=32/128thr (21.5KB LDS); spread
// atomics; padded pyramid + zpad row-select; fastp edge path.

#define TW 32
#define NTHR 128
#define NIMG 48
#define WIN 42                 // rolling window rows (32 + 10)
#define PQ  32                 // v4f pitch, packed channels, XOR-swizzled
#define NSLOT 256
#define SSTRIDE 16             // 64 B between slots -> 1 cache line each

// padded pyramid geometry (8 zero cols each side)
#define RS1 272
#define RS2 144
#define RS3 80
#define RS4 48
#define IS0 (512L*512)
#define IS1 (256L*272)
#define IS2 (128L*144)
#define IS3 (64L*80)
#define IS4 (32L*48)

typedef float v4f __attribute__((ext_vector_type(4)));

struct Pyr {
    float *x1, *y1, *x2, *y2, *x3, *y3, *x4, *y4;
};

__device__ __forceinline__ void h_load(
    const float* __restrict__ xi, const float* __restrict__ yi,
    const float* __restrict__ zpad, int gr, int gc0, int H, int W,
    bool fastp, int rowStride, float* xv, float* yv)
{
    const bool rok = ((unsigned)gr < (unsigned)H);
    if (fastp) {
        const float* px = rok ? (xi + (long)gr * rowStride + gc0) : zpad;
        const float* py = rok ? (yi + (long)gr * rowStride + gc0) : zpad;
#pragma unroll
        for (int v = 0; v < 6; ++v) {
            const float4 a = reinterpret_cast<const float4*>(px)[v];
            const float4 b = reinterpret_cast<const float4*>(py)[v];
            xv[4*v+0]=a.x; xv[4*v+1]=a.y; xv[4*v+2]=a.z; xv[4*v+3]=a.w;
            yv[4*v+0]=b.x; yv[4*v+1]=b.y; yv[4*v+2]=b.z; yv[4*v+3]=b.w;
        }
    } else {
        const float* xrow = xi + (long)gr * rowStride;
        const float* yrow = yi + (long)gr * rowStride;
#pragma unroll
        for (int k = 3; k < 21; ++k) {
            const int gc = gc0 + k;
            const bool ok = rok && ((unsigned)gc < (unsigned)W);
            xv[k] = ok ? xrow[gc] : 0.0f;
            yv[k] = ok ? yrow[gc] : 0.0f;
        }
    }
}

// H-conv 8 output cols, packed channels (x, y, x^2+y^2, xy) -> one b128/col
__device__ __forceinline__ void h_conv_write(
    const float* xv, const float* yv, v4f* smA, int slot, int cb,
    const float* G)
{
    v4f s[8];
#pragma unroll
    for (int j = 0; j < 8; ++j) s[j] = {0.f, 0.f, 0.f, 0.f};
#pragma unroll
    for (int m = 0; m < 18; ++m) {
        const float a = xv[m+3], b = yv[m+3];
        v4f w; w.x = a; w.y = b; w.z = a*a + b*b; w.w = a*b;
#pragma unroll
        for (int j = 0; j < 8; ++j) {
            if (j <= m && m - j <= 10) {
                s[j] += w * G[m - j];              // 2x v_pk_fma_f32
            }
        }
    }
    const int u = slot & 31;
#pragma unroll
    for (int j = 0; j < 8; ++j)
        smA[slot * PQ + ((cb + j) ^ u)] = s[j];    // ds_write_b128
}

// V-conv 8 output rows at col c + SSIM epilogue; returns partial sum
__device__ __forceinline__ float v_phase(
    const v4f* smA, int vb, int c, int rr0, int R0, int C0, int H, int W,
    const float* G)
{
    const float C1 = 4.0e-4f;
    const float C2 = 3.6e-3f;
    v4f acc[8];
#pragma unroll
    for (int i = 0; i < 8; ++i) acc[i] = {0.f, 0.f, 0.f, 0.f};
    int sl = vb;
#pragma unroll
    for (int k = 0; k < 18; ++k) {
        const v4f h = smA[sl * PQ + (c ^ (sl & 31))];  // ds_read_b128
#pragma unroll
        for (int i = 0; i < 8; ++i) {
            if (i <= k && k - i <= 10) {
                acc[i] += h * G[k - i];            // 2x v_pk_fma_f32
            }
        }
        sl = (sl + 1 == WIN) ? 0 : sl + 1;
    }
    float local = 0.f;
    const int gc = C0 + c;
#pragma unroll
    for (int i = 0; i < 8; ++i) {
        const int gr2 = R0 + rr0 + i;
        if (gr2 < H && gc < W) {
            const float mu1 = acc[i].x, mu2 = acc[i].y;
            const float mu1s = mu1*mu1, mu2s = mu2*mu2, m12 = mu1*mu2;
            const float ssum = acc[i].z - mu1s - mu2s;   // sig1+sig2
            const float s12  = acc[i].w - m12;
            const float num = (2.f * m12 + C1) * (2.f * s12 + C2);
            const float den = (mu1s + mu2s + C1) * (ssum + C2);
            local += num * __builtin_amdgcn_rcpf(den + 1e-8f);
        }
    }
    return local;
}

// Full pyramid build for one 32x32 L0 subtile. t < 64 only (wave 0).
// Thread (r, c2) = (t>>3, t&7) owns a 2x2 block of x1 (4x4 of input).
// x2 lane-local; x3/x4 via wave-local shfl quads. Edge blocks zero the
// 8-col pads of every level.
__device__ __forceinline__ void pool_tree(
    const float* __restrict__ xi, const float* __restrict__ yi,
    int t, int R0, int C0, int z, const Pyr& p, int bx)
{
    const int r = t >> 3, c2 = t & 7;
    const int gr = R0 + 4 * r;
    const int gc = C0 + 4 * c2;

    float4 ax[4], ay[4];
#pragma unroll
    for (int rr = 0; rr < 4; ++rr) {
        ax[rr] = *reinterpret_cast<const float4*>(xi + (long)(gr+rr)*512 + gc);
        ay[rr] = *reinterpret_cast<const float4*>(yi + (long)(gr+rr)*512 + gc);
    }
    float qx[2][2], qy[2][2];
#pragma unroll
    for (int i = 0; i < 2; ++i) {
        qx[i][0] = 0.25f*(ax[2*i].x+ax[2*i].y+ax[2*i+1].x+ax[2*i+1].y);
        qx[i][1] = 0.25f*(ax[2*i].z+ax[2*i].w+ax[2*i+1].z+ax[2*i+1].w);
        qy[i][0] = 0.25f*(ay[2*i].x+ay[2*i].y+ay[2*i+1].x+ay[2*i+1].y);
        qy[i][1] = 0.25f*(ay[2*i].z+ay[2*i].w+ay[2*i+1].z+ay[2*i+1].w);
    }
    float* x1p = p.x1 + z*IS1;  float* y1p = p.y1 + z*IS1;
    float* x2p = p.x2 + z*IS2;  float* y2p = p.y2 + z*IS2;
    float* x3p = p.x3 + z*IS3;  float* y3p = p.y3 + z*IS3;
    float* x4p = p.x4 + z*IS4;  float* y4p = p.y4 + z*IS4;

    const int r1 = (R0 >> 1) + 2*r, c1 = (C0 >> 1) + 2*c2;
#pragma unroll
    for (int i = 0; i < 2; ++i) {
        *reinterpret_cast<float2*>(x1p + (long)(r1+i)*RS1 + c1) =
            make_float2(qx[i][0], qx[i][1]);
        *reinterpret_cast<float2*>(y1p + (long)(r1+i)*RS1 + c1) =
            make_float2(qy[i][0], qy[i][1]);
    }
    // x2: lane-local
    const float v2x = 0.25f*(qx[0][0]+qx[0][1]+qx[1][0]+qx[1][1]);
    const float v2y = 0.25f*(qy[0][0]+qy[0][1]+qy[1][0]+qy[1][1]);
    x2p[(long)((R0>>2)+r)*RS2 + (C0>>2)+c2] = v2x;
    y2p[(long)((R0>>2)+r)*RS2 + (C0>>2)+c2] = v2y;
    // x3: quad {t, t+1, t+8, t+9}
    const float v3x = 0.25f*(v2x + __shfl_down(v2x,1,64)
                           + __shfl_down(v2x,8,64) + __shfl_down(v2x,9,64));
    const float v3y = 0.25f*(v2y + __shfl_down(v2y,1,64)
                           + __shfl_down(v2y,8,64) + __shfl_down(v2y,9,64));
    if (!(r & 1) && !(c2 & 1)) {
        x3p[(long)((R0>>3)+(r>>1))*RS3 + (C0>>3)+(c2>>1)] = v3x;
        y3p[(long)((R0>>3)+(r>>1))*RS3 + (C0>>3)+(c2>>1)] = v3y;
    }
    // x4: quad {t, t+2, t+16, t+18} (valid where r%4==0, c2%4==0)
    const float v4x = 0.25f*(v3x + __shfl_down(v3x,2,64)
                           + __shfl_down(v3x,16,64) + __shfl_down(v3x,18,64));
    const float v4y = 0.25f*(v3y + __shfl_down(v3y,2,64)
                           + __shfl_down(v3y,16,64) + __shfl_down(v3y,18,64));
    if (!(r & 3) && !(c2 & 3)) {
        x4p[(long)((R0>>4)+(r>>2))*RS4 + (C0>>4)+(c2>>2)] = v4x;
        y4p[(long)((R0>>4)+(r>>2))*RS4 + (C0>>4)+(c2>>2)] = v4y;
    }
    // pads (8 cols each side), all levels, edge blocks only
    if (bx == 0) {
#pragma unroll
        for (int i = 0; i < 2; ++i) {
            x1p[(long)(r1+i)*RS1 + (c2-8)] = 0.f;
            y1p[(long)(r1+i)*RS1 + (c2-8)] = 0.f;
        }
        x2p[(long)((R0>>2)+r)*RS2 + (c2-8)] = 0.f;
        y2p[(long)((R0>>2)+r)*RS2 + (c2-8)] = 0.f;
        if (r < 4) { x3p[(long)((R0>>3)+r)*RS3 + (c2-8)] = 0.f;
                     y3p[(long)((R0>>3)+r)*RS3 + (c2-8)] = 0.f; }
        if (r < 2) { x4p[(long)((R0>>4)+r)*RS4 + (c2-8)] = 0.f;
                     y4p[(long)((R0>>4)+r)*RS4 + (c2-8)] = 0.f; }
    }
    if (bx == 15) {
#pragma unroll
        for (int i = 0; i < 2; ++i) {
            x1p[(long)(r1+i)*RS1 + 256 + c2] = 0.f;
            y1p[(long)(r1+i)*RS1 + 256 + c2] = 0.f;
        }
        x2p[(long)((R0>>2)+r)*RS2 + 128 + c2] = 0.f;
        y2p[(long)((R0>>2)+r)*RS2 + 128 + c2] = 0.f;
        if (r < 4) { x3p[(long)((R0>>3)+r)*RS3 + 64 + c2] = 0.f;
                     y3p[(long)((R0>>3)+r)*RS3 + 64 + c2] = 0.f; }
        if (r < 2) { x4p[(long)((R0>>4)+r)*RS4 + 32 + c2] = 0.f;
                     y4p[(long)((R0>>4)+r)*RS4 + 32 + c2] = 0.f; }
    }
}

// ---- level 0: SSIM + full pyramid build. 3072 blocks x 128 thr ----
__global__ __launch_bounds__(NTHR, 2) void ssim_l0_kernel(
    const float* __restrict__ x, const float* __restrict__ y,
    Pyr p, const float* __restrict__ zpad, float* __restrict__ slots)
{
    const float G[11] = {
        0.00102839f, 0.00759877f, 0.03600077f, 0.10936069f, 0.21300539f,
        0.26601173f, 0.21300539f, 0.10936069f, 0.03600077f, 0.00759877f,
        0.00102839f};

    __shared__ __align__(16) v4f smA[WIN * PQ];   // 21504 B

    const int t    = threadIdx.x;
    const int bid  = blockIdx.x;
    const int tile = (bid & 7) * 384 + (bid >> 3);     // XCD-contiguous
    const int bx   = tile & 15;
    const int by   = (tile >> 4) & 3;
    const int z    = tile >> 6;
    const int C0   = bx * TW;
    const int S0   = by * 128;
    const float* xi = x + (long)z * IS0;
    const float* yi = y + (long)z * IS0;
    const bool fastp = (C0 >= 8) && (C0 + TW + 8 <= 512);

    // prologue: window rows [S0-5, S0+37)
    for (int s = t; s < WIN * 4; s += NTHR) {
        const int r = s % WIN, q = s / WIN;
        float pxv[24], pyv[24];
        h_load(xi, yi, zpad, S0 + r - 5, C0 + (q << 3) - 8, 512, 512, fastp,
               512, pxv, pyv);
        h_conv_write(pxv, pyv, smA, r, q << 3, G);
    }
    __syncthreads();

    const int c    = t & 31;
    const int rr0  = (t >> 5) * 8;
    const int hr   = t & 31, hq = t >> 5;
    const int hgc0 = C0 + (hq << 3) - 8;
    int wslot = hr, vb = rr0;
    float local = 0.f;

    for (int tt = 0; tt < 3; ++tt) {
        const int R0 = S0 + 32 * tt;
        float xv[24], yv[24];
        h_load(xi, yi, zpad, R0 + 37 + hr, hgc0, 512, 512, fastp, 512, xv, yv);
        local += v_phase(smA, vb, c, rr0, R0, C0, 512, 512, G);
        if (t < 64) pool_tree(xi, yi, t, R0, C0, z, p, bx);
        __syncthreads();
        h_conv_write(xv, yv, smA, wslot, hq << 3, G);
        __syncthreads();
        wslot += 32; if (wslot >= WIN) wslot -= WIN;
        vb    += 32; if (vb    >= WIN) vb    -= WIN;
    }
    {   // peeled tail
        const int R0 = S0 + 96;
        local += v_phase(smA, vb, c, rr0, R0, C0, 512, 512, G);
        if (t < 64) pool_tree(xi, yi, t, R0, C0, z, p, bx);
    }

#pragma unroll
    for (int off = 32; off > 0; off >>= 1) local += __shfl_down(local, off, 64);
    if ((t & 63) == 0) {
        const int slot = ((tile << 1) | (t >> 6)) & (NSLOT - 1);
        atomicAdd(slots + slot * SSTRIDE, local);
    }
}

// ---- levels 1-4 merged: 1536 + 768 + 192 + 48 = 2544 blocks ----
__global__ __launch_bounds__(NTHR, 2) void ssim_lvls_kernel(
    Pyr p, const float* __restrict__ zpad, float* __restrict__ slots)
{
    const float G[11] = {
        0.00102839f, 0.00759877f, 0.03600077f, 0.10936069f, 0.21300539f,
        0.26601173f, 0.21300539f, 0.10936069f, 0.03600077f, 0.00759877f,
        0.00102839f};

    __shared__ __align__(16) v4f smA[WIN * PQ];

    const int t    = threadIdx.x;
    const int bid  = blockIdx.x;
    const int tile = (bid % 8) * 318 + (bid / 8);      // XCD-contiguous

    const float* xi; const float* yi;
    int rowStride, H, C0, S0, nsub, lvl, rem;
    if (tile < 1536) {
        rem = tile; lvl = 1; nsub = 2;
        const int bx = rem & 7, by = (rem >> 3) & 3, z = rem >> 5;
        xi = p.x1 + (long)z * IS1; yi = p.y1 + (long)z * IS1;
        rowStride = RS1; H = 256; C0 = bx * TW; S0 = by * 64;
    } else if (tile < 2304) {
        rem = tile - 1536; lvl = 2; nsub = 1;
        const int bx = rem & 3, by = (rem >> 2) & 3, z = rem >> 4;
        xi = p.x2 + (long)z * IS2; yi = p.y2 + (long)z * IS2;
        rowStride = RS2; H = 128; C0 = bx * TW; S0 = by * 32;
    } else if (tile < 2496) {
        rem = tile - 2304; lvl = 3; nsub = 1;
        const int bx = rem & 1, by = (rem >> 1) & 1, z = rem >> 2;
        xi = p.x3 + (long)z * IS3; yi = p.y3 + (long)z * IS3;
        rowStride = RS3; H = 64; C0 = bx * TW; S0 = by * 32;
    } else {
        rem = tile - 2496; lvl = 4; nsub = 1;
        const int z = rem;
        xi = p.x4 + (long)z * IS4; yi = p.y4 + (long)z * IS4;
        rowStride = RS4; H = 32; C0 = 0; S0 = 0;
    }

    // prologue (pad=1 -> fastp always)
    for (int s = t; s < WIN * 4; s += NTHR) {
        const int r = s % WIN, q = s / WIN;
        float pxv[24], pyv[24];
        h_load(xi, yi, zpad, S0 + r - 5, C0 + (q << 3) - 8, H, H, true,
               rowStride, pxv, pyv);
        h_conv_write(pxv, pyv, smA, r, q << 3, G);
    }
    __syncthreads();

    const int c    = t & 31;
    const int rr0  = (t >> 5) * 8;
    const int hr   = t & 31, hq = t >> 5;
    int wslot = hr, vb = rr0;
    float local = 0.f;

    for (int tt = 0; tt < nsub - 1; ++tt) {
        const int R0 = S0 + 32 * tt;
        float xv[24], yv[24];
        h_load(xi, yi, zpad, R0 + 37 + hr, C0 + (hq << 3) - 8, H, H, true,
               rowStride, xv, yv);
        local += v_phase(smA, vb, c, rr0, R0, C0, H, H, G);
        __syncthreads();
        h_conv_write(xv, yv, smA, wslot, hq << 3, G);
        __syncthreads();
        wslot += 32; if (wslot >= WIN) wslot -= WIN;
        vb    += 32; if (vb    >= WIN) vb    -= WIN;
    }
    local += v_phase(smA, vb, c, rr0, S0 + 32 * (nsub - 1), C0, H, H, G);

#pragma unroll
    for (int off = 32; off > 0; off >>= 1) local += __shfl_down(local, off, 64);
    if ((t & 63) == 0) {
        const int slot = ((rem << 1) | (t >> 6)) & (NSLOT - 1);
        atomicAdd(slots + ((long)lvl * NSLOT + slot) * SSTRIDE, local);
    }
}

__global__ void finalize_kernel(const float* __restrict__ slots,
                                float* __restrict__ out)
{
    const int t = threadIdx.x;
    const float w[5] = {0.0448f, 0.2856f, 0.3001f, 0.2363f, 0.1333f};
    const float wsum = w[0] + w[1] + w[2] + w[3] + w[4];
    float acc = 0.f;
#pragma unroll
    for (int lvl = 0; lvl < 5; ++lvl) {
        const int d = 512 >> lvl;
        const float cnt = (float)NIMG * (float)d * (float)d;
        acc += (w[lvl] / wsum) / cnt * slots[(lvl * NSLOT + t) * SSTRIDE];
    }
#pragma unroll
    for (int off = 32; off > 0; off >>= 1) acc += __shfl_down(acc, off, 64);
    __shared__ float pp[4];
    if ((t & 63) == 0) pp[t >> 6] = acc;
    __syncthreads();
    if (t == 0) out[0] = 1.0f - (pp[0] + pp[1] + pp[2] + pp[3]);
}

extern "C" void kernel_launch(void* const* d_in, const int* in_sizes, int n_in,
                              void* d_out, int out_size, void* d_ws, size_t ws_size,
                              hipStream_t stream)
{
    const float* pred = (const float*)d_in[0];
    const float* targ = (const float*)d_in[1];
    float* out = (float*)d_out;
    float* ws  = (float*)d_ws;

    float* slots = ws;                           // 5 * 256 * 16 floats (80 KB)
    float* zpad  = slots + 5 * NSLOT * SSTRIDE;  // 640 zero floats

    Pyr p;
    p.x1 = zpad + 640 + 8;
    p.y1 = p.x1 + NIMG * IS1;
    p.x2 = p.y1 + NIMG * IS1 - 8 + 8;            // keep +8 col-pad base
    p.x2 = p.y1 + NIMG * IS1;                    // (raw base)
    // assign raw bases then offset all by +8 below
    {
        float* b = zpad + 640;
        p.x1 = b + 8;                 b += NIMG * IS1;
        p.y1 = b + 8;                 b += NIMG * IS1;
        p.x2 = b + 8;                 b += NIMG * IS2;
        p.y2 = b + 8;                 b += NIMG * IS2;
        p.x3 = b + 8;                 b += NIMG * IS3;
        p.y3 = b + 8;                 b += NIMG * IS3;
        p.x4 = b + 8;                 b += NIMG * IS4;
        p.y4 = b + 8;
    }

    hipMemsetAsync(ws, 0, (size_t)(5 * NSLOT * SSTRIDE + 640) * sizeof(float),
                   stream);

    // L0: SSIM + full pyramid. 3072 blocks.
    ssim_l0_kernel<<<dim3(3072), NTHR, 0, stream>>>(pred, targ, p, zpad, slots);
    // L1-4 merged: 2544 blocks.
    ssim_lvls_kernel<<<dim3(2544), NTHR, 0, stream>>>(p, zpad, slots);

    finalize_kernel<<<1, 256, 0, stream>>>(slots, out);
}